// Round 10
// baseline (66.423 us; speedup 1.0000x reference)
//
#include <hip/hip_runtime.h>
#include <hip/hip_bf16.h>

typedef short bf16x8 __attribute__((ext_vector_type(8)));
typedef float f32x4  __attribute__((ext_vector_type(4)));

#define NB 64
#define NN 512
#define DD 128

// pack two f32 -> two bf16 (RNE) in one VALU op
__device__ __forceinline__ unsigned int cvt_pk_bf16(float lo, float hi) {
    unsigned int r;
    asm("v_cvt_pk_bf16_f32 %0, %1, %2" : "=v"(r) : "v"(lo), "v"(hi));
    return r;
}

// load 8 consecutive f32, convert to a bf16x8 MFMA fragment (4 cvt_pk)
__device__ __forceinline__ bf16x8 load_frag8_f32(const float* __restrict__ p) {
    const f32x4 a = *reinterpret_cast<const f32x4*>(p);
    const f32x4 b = *reinterpret_cast<const f32x4*>(p + 4);
    union { unsigned int u[4]; bf16x8 v; } r;
    r.u[0] = cvt_pk_bf16(a[0], a[1]);
    r.u[1] = cvt_pk_bf16(a[2], a[3]);
    r.u[2] = cvt_pk_bf16(b[0], b[1]);
    r.u[3] = cvt_pk_bf16(b[2], b[3]);
    return r.v;
}

// Kernel 1: reciprocal row norms only (128 KB output). XCD-pinned so each
// batch's fea slice is pulled into the L2 of the XCD that consumes it.
__global__ __launch_bounds__(256) void ASG_rs_kernel(
    const float* __restrict__ fea, float* __restrict__ rs)
{
    const int id  = blockIdx.x;         // 0..511
    const int xcd = id & 7;
    const int q   = id >> 3;            // 0..63
    const int b   = xcd + 8 * (q >> 3);
    const int t   = q & 7;              // 64-row chunk within batch
    const int wid = threadIdx.x >> 6, lane = threadIdx.x & 63;
    const int base = b * NN + t * 64;   // block's 64 rows (global row idx)
    const int row0 = base + wid * 16;   // wave's 16 rows
    const float2* src = reinterpret_cast<const float2*>(fea);

    __shared__ float lrs[64];

#pragma unroll
    for (int g = 0; g < 4; ++g) {
        float2 v[4];
        float  s[4];
#pragma unroll
        for (int rr = 0; rr < 4; ++rr) {
            v[rr] = src[(size_t)(row0 + g * 4 + rr) * (DD / 2) + lane];
            s[rr] = v[rr].x * v[rr].x + v[rr].y * v[rr].y;
        }
#pragma unroll
        for (int o = 32; o; o >>= 1) {
#pragma unroll
            for (int rr = 0; rr < 4; ++rr) s[rr] += __shfl_xor(s[rr], o);
        }
        if (lane == 0) {
#pragma unroll
            for (int rr = 0; rr < 4; ++rr)
                lrs[wid * 16 + g * 4 + rr] =
                    1.0f / fmaxf(sqrtf(s[rr]), 1e-8f);
        }
    }
    __syncthreads();
    if (threadIdx.x < 64) rs[base + threadIdx.x] = lrs[threadIdx.x];
}

// Kernel 2: R8 structure exactly (per (batch, 128x64 tile), 4 waves x
// 64x32, per-m interleave, LDS transpose, plain x4 stores, A-prefetch) —
// but fragments load raw f32 fea with in-flight cvt_pk, and rs_i*rs_j is
// applied in the epilogue. No fn workspace round-trip.
__global__ __launch_bounds__(256, 4) void ASG_adj_kernel(
    const float* __restrict__ fea, const float* __restrict__ coord,
    const float* __restrict__ rsbuf, float* __restrict__ out)
{
    const int id  = blockIdx.x;        // 0..2047
    const int xcd = id & 7;
    const int q   = id >> 3;           // 0..255
    const int b   = xcd + 8 * (q >> 5);
    const int t   = q & 31;
    const int bi  = t >> 3;            // 128-row stripe 0..3
    const int bj  = t & 7;             // 64-col stripe 0..7

    const int tid = threadIdx.x;
    const int wid = tid >> 6, lane = tid & 63;
    const int wr  = wid >> 1, wc = wid & 1;
    const int row0 = bi * 128 + wr * 64;
    const int col0 = bj * 64  + wc * 32;
    const int lo = lane & 15, hi = lane >> 4;

    __shared__ float2 crow[128];
    __shared__ float2 ccol[64];
    alignas(16) __shared__ float rsA[128];
    alignas(16) __shared__ float rsB[64];
    __shared__ float xpose[4][16 * 36];    // per-wave transpose buf (pad 36)

    const float2* cb = reinterpret_cast<const float2*>(coord) + (size_t)b * NN;
    if (tid < 128) {
        crow[tid] = cb[bi * 128 + tid];
        rsA[tid]  = rsbuf[b * NN + bi * 128 + tid];
    } else if (tid < 192) {
        const int u = tid - 128;
        ccol[u] = cb[bj * 64 + u];
        rsB[u]  = rsbuf[b * NN + bj * 64 + u];
    }
    __syncthreads();

    const float* feab = fea + (size_t)b * NN * DD;
    const int lk = hi * 8;             // k start (f32 elements)

    // B fragments: col = col0 + n*16 + lo (loop-invariant)
    bf16x8 bfrag[2][4];
#pragma unroll
    for (int n = 0; n < 2; ++n) {
        const float* p = feab + (size_t)(col0 + n * 16 + lo) * DD + lk;
#pragma unroll
        for (int kk = 0; kk < 4; ++kk)
            bfrag[n][kk] = load_frag8_f32(p + kk * 32);
    }

    float* outA = out + (size_t)b * NN * NN;
    float* outS = out + (size_t)NB * NN * NN + (size_t)b * NN * NN;
    float* xp = xpose[wid];

    // this lane's 4 output columns (after transpose): jbase..jbase+3
    const int c4 = (lane & 7) * 4;
    const int jbase = col0 + c4;
    float2 cj[4];
#pragma unroll
    for (int q2 = 0; q2 < 4; ++q2) cj[q2] = ccol[wc * 32 + c4 + q2];
    const f32x4 rsj = *reinterpret_cast<const f32x4*>(&rsB[wc * 32 + c4]);

#define LOADA(DST, MM)                                                        \
    {                                                                         \
        const float* p = feab + (size_t)(row0 + (MM) * 16 + lo) * DD + lk;    \
        _Pragma("unroll")                                                     \
        for (int kk = 0; kk < 4; ++kk)                                        \
            DST[kk] = load_frag8_f32(p + kk * 32);                            \
    }

#define STEP(MM, CURF, NEXTF, DO_PREF)                                        \
    {                                                                         \
        if (DO_PREF) LOADA(NEXTF, (MM) + 1);                                  \
        f32x4 acc[2];                                                         \
        _Pragma("unroll")                                                     \
        for (int n = 0; n < 2; ++n) acc[n] = (f32x4){0.f, 0.f, 0.f, 0.f};     \
        _Pragma("unroll")                                                     \
        for (int n = 0; n < 2; ++n)                                           \
            _Pragma("unroll")                                                 \
            for (int kk = 0; kk < 4; ++kk)                                    \
                acc[n] = __builtin_amdgcn_mfma_f32_16x16x32_bf16(             \
                    CURF[kk], bfrag[n][kk], acc[n], 0, 0, 0);                 \
        /* scatter into LDS: [local_row][local_col], stride 36 */             \
        _Pragma("unroll")                                                     \
        for (int n = 0; n < 2; ++n)                                           \
            _Pragma("unroll")                                                 \
            for (int r = 0; r < 4; ++r)                                       \
                xp[(hi * 4 + r) * 36 + n * 16 + lo] = acc[n][r];              \
        /* read back transposed: 8 rows x 32 cols per pass, x4/lane */        \
        _Pragma("unroll")                                                     \
        for (int p2 = 0; p2 < 2; ++p2) {                                      \
            const int rr = p2 * 8 + (lane >> 3);       /* local row 0..15 */  \
            const f32x4 cv =                                                  \
                *reinterpret_cast<const f32x4*>(&xp[rr * 36 + c4]);           \
            const int i = row0 + (MM) * 16 + rr;                              \
            const float rsi = rsA[wr * 64 + (MM) * 16 + rr];                  \
            const float2 ci = crow[wr * 64 + (MM) * 16 + rr];                 \
            f32x4 av, sv;                                                     \
            _Pragma("unroll")                                                 \
            for (int q2 = 0; q2 < 4; ++q2) {                                  \
                const int j = jbase + q2;                                     \
                /* bit-exact numpy chain: mul, mul, add, sqrt (no FMA) */     \
                const float dx = ci.x - cj[q2].x;                             \
                const float dy = ci.y - cj[q2].y;                             \
                const float d2 =                                              \
                    __fadd_rn(__fmul_rn(dx, dx), __fmul_rn(dy, dy));          \
                const float dist = __fsqrt_rn(d2);                            \
                const bool diag = (i == j);                                   \
                av[q2] = diag ? 0.0f                                          \
                              : cv[q2] * rsi * rsj[q2] * __expf(-dist);       \
                sv[q2] = (!diag && dist < 1.0f) ? 1.0f : 0.0f;                \
            }                                                                 \
            const size_t off = (size_t)i * NN + jbase;                        \
            *reinterpret_cast<f32x4*>(outA + off) = av;                       \
            *reinterpret_cast<f32x4*>(outS + off) = sv;                       \
        }                                                                     \
    }

    bf16x8 af0[4], af1[4];
    LOADA(af0, 0);
    STEP(0, af0, af1, 1);
    STEP(1, af1, af0, 1);
    STEP(2, af0, af1, 1);
    STEP(3, af1, af0, 0);

#undef STEP
#undef LOADA
}

extern "C" void kernel_launch(void* const* d_in, const int* in_sizes, int n_in,
                              void* d_out, int out_size, void* d_ws, size_t ws_size,
                              hipStream_t stream) {
    const float* fea   = (const float*)d_in[0];   // [64,512,128] f32
    const float* coord = (const float*)d_in[1];   // [64,512,2]   f32
    float* out = (float*)d_out;                   // [2,64,512,512] f32
    float* rs_ws = (float*)d_ws;                  // 32768 f32 = 128 KB

    ASG_rs_kernel<<<dim3(512), 256, 0, stream>>>(fea, rs_ws);
    ASG_adj_kernel<<<dim3(2048), 256, 0, stream>>>(fea, coord, rs_ws, out);
}

// Round 11
// 53.178 us; speedup vs baseline: 1.2491x; 1.2491x over previous
//
#include <hip/hip_runtime.h>
#include <hip/hip_bf16.h>

typedef short bf16x8 __attribute__((ext_vector_type(8)));
typedef float f32x4  __attribute__((ext_vector_type(4)));

#define NB 64
#define NN 512
#define DD 128

// RNE float -> bf16 (finite inputs)
__device__ __forceinline__ unsigned short f2bf(float f) {
    unsigned int u = __float_as_uint(f);
    unsigned int r = (u + 0x7FFFu + ((u >> 16) & 1u)) >> 16;
    return (unsigned short)r;
}

// Kernel 1: per-row L2 normalize, write bf16 fn into workspace (XCD-pinned).
__global__ __launch_bounds__(256) void ASG_norm_kernel(
    const float* __restrict__ fea, unsigned int* __restrict__ fn)
{
    const int id   = blockIdx.x;        // 0..2047
    const int xcd  = id & 7;
    const int q    = id >> 3;           // 0..255
    const int b    = xcd + 8 * (q >> 5);
    const int t    = q & 31;            // 32 blocks/batch, 16 rows each
    const int wid  = threadIdx.x >> 6;
    const int lane = threadIdx.x & 63;
    const int row0 = b * NN + t * 16 + wid * 4;
    const float2* src = reinterpret_cast<const float2*>(fea);

    float2 v[4];
    float  s[4];
#pragma unroll
    for (int rr = 0; rr < 4; ++rr) {
        v[rr] = src[(size_t)(row0 + rr) * (DD / 2) + lane];
        s[rr] = v[rr].x * v[rr].x + v[rr].y * v[rr].y;
    }
#pragma unroll
    for (int o = 32; o; o >>= 1) {
#pragma unroll
        for (int rr = 0; rr < 4; ++rr) s[rr] += __shfl_xor(s[rr], o);
    }
#pragma unroll
    for (int rr = 0; rr < 4; ++rr) {
        const float scale = 1.0f / fmaxf(sqrtf(s[rr]), 1e-8f);
        const unsigned short a = f2bf(v[rr].x * scale);
        const unsigned short bb = f2bf(v[rr].y * scale);
        fn[(size_t)(row0 + rr) * (DD / 2) + lane] =
            (unsigned int)a | ((unsigned int)bb << 16);
    }
}

// Kernel A: async plane only. R8 structure exactly (bf16 frags, per-m
// interleave, LDS transpose, plain x4 stores, A-prefetch) minus the sv
// plane -> half the stores.
__global__ __launch_bounds__(256, 4) void ASG_async_kernel(
    const unsigned short* __restrict__ fn, const float* __restrict__ coord,
    float* __restrict__ out)
{
    const int id  = blockIdx.x;        // 0..2047
    const int xcd = id & 7;
    const int q   = id >> 3;           // 0..255
    const int b   = xcd + 8 * (q >> 5);
    const int t   = q & 31;
    const int bi  = t >> 3;            // 128-row stripe 0..3
    const int bj  = t & 7;             // 64-col stripe 0..7

    const int tid = threadIdx.x;
    const int wid = tid >> 6, lane = tid & 63;
    const int wr  = wid >> 1, wc = wid & 1;
    const int row0 = bi * 128 + wr * 64;
    const int col0 = bj * 64  + wc * 32;
    const int lo = lane & 15, hi = lane >> 4;

    __shared__ float2 crow[128];
    __shared__ float2 ccol[64];
    __shared__ float  xpose[4][16 * 36];   // per-wave transpose buf (pad 36)

    const float2* cb = reinterpret_cast<const float2*>(coord) + (size_t)b * NN;
    if (tid < 128)      crow[tid] = cb[bi * 128 + tid];
    else if (tid < 192) ccol[tid - 128] = cb[bj * 64 + (tid - 128)];
    __syncthreads();

    const unsigned short* fb = fn + (size_t)b * NN * DD;
    const int lk = hi * 8;             // k start (bf16 elements)

    bf16x8 bfrag[2][4];
#pragma unroll
    for (int n = 0; n < 2; ++n) {
        const unsigned short* p = fb + (size_t)(col0 + n * 16 + lo) * DD + lk;
#pragma unroll
        for (int kk = 0; kk < 4; ++kk)
            bfrag[n][kk] = *reinterpret_cast<const bf16x8*>(p + kk * 32);
    }

    float* outA = out + (size_t)b * NN * NN;
    float* xp = xpose[wid];

    const int c4 = (lane & 7) * 4;
    const int jbase = col0 + c4;
    float2 cj[4];
#pragma unroll
    for (int q2 = 0; q2 < 4; ++q2) cj[q2] = ccol[wc * 32 + c4 + q2];

#define LOADA(DST, MM)                                                        \
    {                                                                         \
        const unsigned short* p =                                             \
            fb + (size_t)(row0 + (MM) * 16 + lo) * DD + lk;                   \
        _Pragma("unroll")                                                     \
        for (int kk = 0; kk < 4; ++kk)                                        \
            DST[kk] = *reinterpret_cast<const bf16x8*>(p + kk * 32);          \
    }

#define STEP(MM, CURF, NEXTF, DO_PREF)                                        \
    {                                                                         \
        if (DO_PREF) LOADA(NEXTF, (MM) + 1);                                  \
        f32x4 acc[2];                                                         \
        _Pragma("unroll")                                                     \
        for (int n = 0; n < 2; ++n) acc[n] = (f32x4){0.f, 0.f, 0.f, 0.f};     \
        _Pragma("unroll")                                                     \
        for (int n = 0; n < 2; ++n)                                           \
            _Pragma("unroll")                                                 \
            for (int kk = 0; kk < 4; ++kk)                                    \
                acc[n] = __builtin_amdgcn_mfma_f32_16x16x32_bf16(             \
                    CURF[kk], bfrag[n][kk], acc[n], 0, 0, 0);                 \
        _Pragma("unroll")                                                     \
        for (int n = 0; n < 2; ++n)                                           \
            _Pragma("unroll")                                                 \
            for (int r = 0; r < 4; ++r)                                       \
                xp[(hi * 4 + r) * 36 + n * 16 + lo] = acc[n][r];              \
        _Pragma("unroll")                                                     \
        for (int p2 = 0; p2 < 2; ++p2) {                                      \
            const int rr = p2 * 8 + (lane >> 3);       /* local row 0..15 */  \
            const f32x4 cv =                                                  \
                *reinterpret_cast<const f32x4*>(&xp[rr * 36 + c4]);           \
            const int i = row0 + (MM) * 16 + rr;                              \
            const float2 ci = crow[wr * 64 + (MM) * 16 + rr];                 \
            f32x4 av;                                                         \
            _Pragma("unroll")                                                 \
            for (int q2 = 0; q2 < 4; ++q2) {                                  \
                const int j = jbase + q2;                                     \
                /* bit-exact numpy chain: mul, mul, add, sqrt (no FMA) */     \
                const float dx = ci.x - cj[q2].x;                             \
                const float dy = ci.y - cj[q2].y;                             \
                const float d2 =                                              \
                    __fadd_rn(__fmul_rn(dx, dx), __fmul_rn(dy, dy));          \
                const float dist = __fsqrt_rn(d2);                            \
                const bool diag = (i == j);                                   \
                av[q2] = diag ? 0.0f : cv[q2] * __expf(-dist);                \
            }                                                                 \
            *reinterpret_cast<f32x4*>(outA + (size_t)i * NN + jbase) = av;    \
        }                                                                     \
    }

    bf16x8 af0[4], af1[4];
    LOADA(af0, 0);
    STEP(0, af0, af1, 1);
    STEP(1, af1, af0, 1);
    STEP(2, af0, af1, 1);
    STEP(3, af1, af0, 0);

#undef STEP
#undef LOADA
}

// Kernel B: sync plane only — coord in, 0/1 out. Near-pure write stream:
// block = (batch, 16 rows); wave stores 1KB-contiguous per instruction.
__global__ __launch_bounds__(256) void ASG_sync_kernel(
    const float* __restrict__ coord, float* __restrict__ outS)
{
    const int bid = blockIdx.x;        // 0..2047
    const int b   = bid >> 5;
    const int i0  = (bid & 31) * 16;   // 16 rows
    const int tid = threadIdx.x;

    __shared__ float2 ccol[NN];
    __shared__ float2 crow[16];
    const float2* cb = reinterpret_cast<const float2*>(coord) + (size_t)b * NN;
    ccol[tid]       = cb[tid];
    ccol[tid + 256] = cb[tid + 256];
    if (tid < 16) crow[tid] = cb[i0 + tid];
    __syncthreads();

    const int half = tid >> 7;         // 0/1
    const int col  = (tid & 127) * 4;  // 128 threads cover 512 cols
    float2 cj[4];
#pragma unroll
    for (int c = 0; c < 4; ++c) cj[c] = ccol[col + c];

    float* o = outS + (size_t)b * NN * NN;
#pragma unroll
    for (int rr = 0; rr < 8; ++rr) {
        const int lr = rr * 2 + half;
        const int i  = i0 + lr;
        const float2 ci = crow[lr];
        f32x4 sv;
#pragma unroll
        for (int c = 0; c < 4; ++c) {
            // bit-exact numpy chain: mul, mul, add, sqrt (no FMA)
            const float dx = ci.x - cj[c].x;
            const float dy = ci.y - cj[c].y;
            const float d2 = __fadd_rn(__fmul_rn(dx, dx), __fmul_rn(dy, dy));
            const float dist = __fsqrt_rn(d2);
            const bool diag = (i == col + c);
            sv[c] = (!diag && dist < 1.0f) ? 1.0f : 0.0f;
        }
        *reinterpret_cast<f32x4*>(o + (size_t)i * NN + col) = sv;
    }
}

extern "C" void kernel_launch(void* const* d_in, const int* in_sizes, int n_in,
                              void* d_out, int out_size, void* d_ws, size_t ws_size,
                              hipStream_t stream) {
    const float* fea   = (const float*)d_in[0];   // [64,512,128] f32
    const float* coord = (const float*)d_in[1];   // [64,512,2]   f32
    float* out = (float*)d_out;                   // [2,64,512,512] f32
    unsigned int* fn_ws = (unsigned int*)d_ws;    // bf16 fn, 8 MB

    ASG_norm_kernel<<<dim3(2048), 256, 0, stream>>>(fea, fn_ws);
    ASG_async_kernel<<<dim3(2048), 256, 0, stream>>>(
        (const unsigned short*)fn_ws, coord, out);
    ASG_sync_kernel<<<dim3(2048), 256, 0, stream>>>(
        coord, out + (size_t)NB * NN * NN);
}

// Round 12
// 43.837 us; speedup vs baseline: 1.5152x; 1.2131x over previous
//
#include <hip/hip_runtime.h>
#include <hip/hip_bf16.h>

typedef short bf16x8 __attribute__((ext_vector_type(8)));
typedef float f32x4  __attribute__((ext_vector_type(4)));

#define NB 64
#define NN 512
#define DD 128

// RNE float -> bf16 (finite inputs)
__device__ __forceinline__ unsigned short f2bf(float f) {
    unsigned int u = __float_as_uint(f);
    unsigned int r = (u + 0x7FFFu + ((u >> 16) & 1u)) >> 16;
    return (unsigned short)r;
}

// read one bf16x8 fragment from LDS as two 8B-aligned reads
__device__ __forceinline__ bf16x8 lds_frag(const unsigned short* p) {
    union { unsigned int u[4]; bf16x8 v; } r;
    const uint2 a = *reinterpret_cast<const uint2*>(p);
    const uint2 b = *reinterpret_cast<const uint2*>(p + 4);
    r.u[0] = a.x; r.u[1] = a.y; r.u[2] = b.x; r.u[3] = b.y;
    return r.v;
}

// Single kernel. Per (batch, 128x64 tile); 4 waves, each owns 64x32.
// Prologue: wave-parallel row norms (2 rows per pass, float4/lane,
// 5-shuffle reduce) writing NORMALIZED bf16 into LDS. MFMA phase reads
// fragments from LDS (ds_read_b64). Direct scattered b32 stores.
// No norm kernel, no fn workspace, no inter-kernel gap.
__global__ __launch_bounds__(256, 3) void ASG_fused_kernel(
    const float* __restrict__ fea, const float* __restrict__ coord,
    float* __restrict__ out)
{
    const int id  = blockIdx.x;        // 0..2047
    const int xcd = id & 7;
    const int q   = id >> 3;           // 0..255
    const int b   = xcd + 8 * (q >> 5);
    const int t   = q & 31;
    const int bi  = t >> 3;            // 128-row stripe 0..3
    const int bj  = t & 7;             // 64-col stripe 0..7

    const int tid = threadIdx.x;
    const int wid = tid >> 6, lane = tid & 63;
    const int wr  = wid >> 1, wc = wid & 1;
    const int row0 = bi * 128 + wr * 64;     // global
    const int col0 = bj * 64  + wc * 32;     // global
    const int lo = lane & 15, hi = lane >> 4;

    // padded stride 132 bf16 (264B): 8B-aligned rows, 2-way-max banks
    __shared__ unsigned short fa[128 * 132];   // normalized A rows (bf16)
    __shared__ unsigned short fbs[64 * 132];   // normalized B rows (bf16)
    __shared__ float2 crow[128];
    __shared__ float2 ccol[64];

    const float* feab = fea + (size_t)b * NN * DD;

    // ---- prologue: 192 row-norms, wave-parallel (48 rows per wave) ----
    {
        const int li = lane & 31;
        const int l5 = lane >> 5;
#pragma unroll 4
        for (int p = 0; p < 24; ++p) {
            const int rr = wid * 48 + p * 2 + l5;         // 0..191
            const int rg = (rr < 128) ? bi * 128 + rr : bj * 64 + (rr - 128);
            const f32x4 v = *reinterpret_cast<const f32x4*>(
                feab + (size_t)rg * DD + li * 4);
            float s = v[0] * v[0] + v[1] * v[1] + v[2] * v[2] + v[3] * v[3];
            s += __shfl_xor(s, 16);
            s += __shfl_xor(s, 8);
            s += __shfl_xor(s, 4);
            s += __shfl_xor(s, 2);
            s += __shfl_xor(s, 1);
            const float rs = 1.0f / fmaxf(sqrtf(s), 1e-8f);
            const unsigned int u0 =
                (unsigned int)f2bf(v[0] * rs) | ((unsigned int)f2bf(v[1] * rs) << 16);
            const unsigned int u1 =
                (unsigned int)f2bf(v[2] * rs) | ((unsigned int)f2bf(v[3] * rs) << 16);
            unsigned short* dst = (rr < 128) ? &fa[rr * 132 + li * 4]
                                             : &fbs[(rr - 128) * 132 + li * 4];
            *reinterpret_cast<unsigned int*>(dst)     = u0;
            *reinterpret_cast<unsigned int*>(dst + 2) = u1;
        }
    }
    const float2* cb = reinterpret_cast<const float2*>(coord) + (size_t)b * NN;
    if (tid < 128)      crow[tid] = cb[bi * 128 + tid];
    else if (tid < 192) ccol[tid - 128] = cb[bj * 64 + (tid - 128)];
    __syncthreads();

    const int lk = hi * 8;             // k start (bf16 elements)

    // B fragments: local col = wc*32 + n*16 + lo (held in regs)
    bf16x8 bfrag[2][4];
#pragma unroll
    for (int n = 0; n < 2; ++n) {
        const unsigned short* p = &fbs[(wc * 32 + n * 16 + lo) * 132 + lk];
#pragma unroll
        for (int kk = 0; kk < 4; ++kk)
            bfrag[n][kk] = lds_frag(p + kk * 32);
    }

    float* outA = out + (size_t)b * NN * NN;
    float* outS = out + (size_t)NB * NN * NN + (size_t)b * NN * NN;

    const int j0 = col0 + lo;
    const int j1 = col0 + 16 + lo;
    const float2 cj0 = ccol[wc * 32 + lo];
    const float2 cj1 = ccol[wc * 32 + 16 + lo];

#pragma unroll
    for (int m = 0; m < 4; ++m) {
        // A fragments for this 16-row group, from LDS
        bf16x8 afrag[4];
        {
            const unsigned short* p = &fa[(wr * 64 + m * 16 + lo) * 132 + lk];
#pragma unroll
            for (int kk = 0; kk < 4; ++kk)
                afrag[kk] = lds_frag(p + kk * 32);
        }

        f32x4 acc0 = (f32x4){0.f, 0.f, 0.f, 0.f};
        f32x4 acc1 = (f32x4){0.f, 0.f, 0.f, 0.f};
#pragma unroll
        for (int kk = 0; kk < 4; ++kk)
            acc0 = __builtin_amdgcn_mfma_f32_16x16x32_bf16(
                afrag[kk], bfrag[0][kk], acc0, 0, 0, 0);
#pragma unroll
        for (int kk = 0; kk < 4; ++kk)
            acc1 = __builtin_amdgcn_mfma_f32_16x16x32_bf16(
                afrag[kk], bfrag[1][kk], acc1, 0, 0, 0);

        // epilogue: MFMA C layout col=lo, row=hi*4+r; direct b32 stores
#pragma unroll
        for (int r = 0; r < 4; ++r) {
            const int i = row0 + m * 16 + hi * 4 + r;
            const float2 ci = crow[wr * 64 + m * 16 + hi * 4 + r];
            // bit-exact numpy chain: mul, mul, add, sqrt (no FMA)
            {
                const float dx = ci.x - cj0.x;
                const float dy = ci.y - cj0.y;
                const float d2 = __fadd_rn(__fmul_rn(dx, dx), __fmul_rn(dy, dy));
                const float dist = __fsqrt_rn(d2);
                const bool diag = (i == j0);
                const float av = diag ? 0.0f : acc0[r] * __expf(-dist);
                const float sv = (!diag && dist < 1.0f) ? 1.0f : 0.0f;
                const size_t off = (size_t)i * NN + j0;
                outA[off] = av;
                outS[off] = sv;
            }
            {
                const float dx = ci.x - cj1.x;
                const float dy = ci.y - cj1.y;
                const float d2 = __fadd_rn(__fmul_rn(dx, dx), __fmul_rn(dy, dy));
                const float dist = __fsqrt_rn(d2);
                const bool diag = (i == j1);
                const float av = diag ? 0.0f : acc1[r] * __expf(-dist);
                const float sv = (!diag && dist < 1.0f) ? 1.0f : 0.0f;
                const size_t off = (size_t)i * NN + j1;
                outA[off] = av;
                outS[off] = sv;
            }
        }
    }
}

extern "C" void kernel_launch(void* const* d_in, const int* in_sizes, int n_in,
                              void* d_out, int out_size, void* d_ws, size_t ws_size,
                              hipStream_t stream) {
    const float* fea   = (const float*)d_in[0];   // [64,512,128] f32
    const float* coord = (const float*)d_in[1];   // [64,512,2]   f32
    float* out = (float*)d_out;                   // [2,64,512,512] f32

    ASG_fused_kernel<<<dim3(2048), 256, 0, stream>>>(fea, coord, out);
}